// Round 5
// baseline (1393.548 us; speedup 1.0000x reference)
//
#include <hip/hip_runtime.h>
#include <cstddef>
#include <cstdint>

// CT-LSTM right-to-left scan, weight-stationary MFMA, tagged-h protocol.
// 128 seqs (B=16,P=8), T=256, H=256, 7H=1792 gate rows, VOCAB=35, IDX_PAD=34.
//
//   z = EW[event]  +  h @ W2^T        (W2 = W[:,256:512], f16)
//
// 16 slices x 4 super-groups = 64 blocks; block (b,p) holds B-fragments for
// hidden j in [16b,16b+16) resident in VGPRs, alternating 2 cohorts of 16 seqs.
//
// Sync: NO flags. h' is published as tagged u32 = (it+1)<<16 | f16bits, one
// per element (4-B stores are atomic -> per-element tags have no data/flag
// race). Readers speculatively load the tagged h a FULL HALF early (RT fully
// hidden), then validate with a pure-VALU tag scan; stale -> reload (rare).
// Publisher side is fire-and-forget: no drain, no flag, no probe, no spin.
//
// All loop VMEM is inline asm in fixed per-wave order
//   [spec-h 16L, spec-EW 8L(4 for wave3), pub 1S, out 6S]
// so the half-start s_waitcnt vmcnt(6) exactly covers all loads + the pub
// store while letting the 6 output stores float across the boundary.

typedef _Float16 hf;
typedef _Float16 f16x8 __attribute__((ext_vector_type(8)));
typedef float    f32x4 __attribute__((ext_vector_type(4)));
typedef uint32_t u32;
typedef uint32_t u32x4 __attribute__((ext_vector_type(4)));

#define HID  256
#define R7   1792
#define TT   256
#define NPAD 34
#define THBUF 4096       // u32 elems per tagged-h buffer (16 seq x 256)

__device__ __forceinline__ float sigf(float x) { return 1.0f / (1.0f + __expf(-x)); }
__device__ __forceinline__ float tanh_f(float x) { return 1.0f - 2.0f / (__expf(2.0f * x) + 1.0f); }
__device__ __forceinline__ float softplusf(float x) {
  return fmaxf(x, 0.0f) + __logf(1.0f + __expf(-fabsf(x)));
}

// ---------------------------------------------------------------------------
// Repack W[:,256:512] into MFMA B-fragment order.
// Entry idx = ((b*7+g)*8 + kt)*64 + lane:
//   B[k = kt*32 + 8*(lane>>4) + e][n = lane&15] = W2[g*256 + 16b + (lane&15)][k]
__global__ __launch_bounds__(256) void repack_mfma(const float* __restrict__ W,
                                                   f16x8* __restrict__ Wf) {
  int idx  = blockIdx.x * 256 + threadIdx.x;  // [0, 57344)
  int lane = idx & 63;
  int kt   = (idx >> 6) & 7;
  int gb   = idx >> 9;            // b*7 + g
  int g    = gb % 7;
  int b    = gb / 7;
  int row  = g * HID + b * 16 + (lane & 15);
  int k0   = kt * 32 + (lane >> 4) * 8;
  const float* src = W + (size_t)row * 512 + 256 + k0;
  f16x8 o;
#pragma unroll
  for (int e = 0; e < 8; ++e) o[e] = (hf)src[e];
  Wf[idx] = o;
}

// ---------------------------------------------------------------------------
// EW[e][r] = sum_k Emb[e][k] * W[r][k] + b[r]   (e<35, r<1792, k<256)
__global__ __launch_bounds__(256) void ew_kernel(const float* __restrict__ Emb,
                                                 const float* __restrict__ W,
                                                 const float* __restrict__ bias,
                                                 float* __restrict__ EW) {
  int wid  = (blockIdx.x * 256 + threadIdx.x) >> 6;
  int lane = threadIdx.x & 63;
  int o    = wid * 4;
#pragma unroll
  for (int qq = 0; qq < 4; ++qq, ++o) {
    int e = o / R7;
    int r = o - e * R7;
    const float4 ev4 = *(const float4*)(Emb + e * HID + lane * 4);
    const float4 wv4 = *(const float4*)(W + (size_t)r * 512 + lane * 4);
    float acc = ev4.x * wv4.x + ev4.y * wv4.y + ev4.z * wv4.z + ev4.w * wv4.w;
#pragma unroll
    for (int m = 32; m >= 1; m >>= 1) acc += __shfl_xor(acc, m, 64);
    if (lane == 0) EW[o] = acc + bias[r];
  }
}

// ---------------------------------------------------------------------------
__global__ __launch_bounds__(256, 1) void scan_mfma(
    const int* __restrict__ event, const float* __restrict__ dtime,
    const float* __restrict__ EW, const f16x8* __restrict__ Wf,
    u32* __restrict__ thbuf, float* __restrict__ out) {
  const int tid = threadIdx.x;
  const int b   = blockIdx.x & 15;   // hidden slice
  const int p   = blockIdx.x >> 4;   // super-group 0..3
  const int j0  = b * 16;
  const int wid = tid >> 6, lane = tid & 63;
  const int seq = tid >> 4, jj = tid & 15;   // epilogue ownership (per cohort)
  const int j   = j0 + jj;
  const int q   = lane >> 4, nn = lane & 15; // MFMA C/D coords

  __shared__ int   evs[32][TT];              // [cohort*16+seq][i]
  __shared__ float dts[32][TT];
  __shared__ __align__(16) float gbuf[7][16][20];  // [gate][n][seq] (pad 20)

#pragma unroll 4
  for (int r = 0; r < 32; ++r) {
    evs[r][tid] = event[(size_t)(p * 32 + r) * TT + tid];
    dts[r][tid] = dtime[(size_t)(p * 32 + r) * TT + tid];
  }

  // Resident B fragments: wave w owns gates {2w, 2w+1} (w==3: gate 6 only).
  const int  g0  = 2 * wid;
  const bool two = (wid < 3);
  f16x8 B0[8], B1[8];
  {
    const f16x8* wsrc = Wf + (size_t)((b * 7 + g0) * 8) * 64 + lane;
#pragma unroll
    for (int kt = 0; kt < 8; ++kt) B0[kt] = wsrc[kt * 64];
    if (two) {
#pragma unroll
      for (int kt = 0; kt < 8; ++kt) B1[kt] = wsrc[(8 + kt) * 64];
    }
  }
  __syncthreads();

  u32* thp = thbuf + (size_t)p * 4 * THBUF;  // [cohort][parity][4096]

  // Writer index in A-fragment order (same lane->k map as the reader).
  const int idx_w = ((j >> 5) * 64 + seq + 16 * ((j >> 3) & 3)) * 8 + (j & 7);
  const size_t OS = 8355840;  // per-output-tensor stride

  float cp0 = 0.f, cb0 = 0.f, cp1 = 0.f, cb1 = 0.f;

  // Cross-half pipelined state.
  u32x4 tv[16];          // tagged h (spec-loaded a full half early)
  float e0[4], e1[4];    // EW C-in values for the current half

  // Prologue: EW for half (0,0) via asm + full drain, then pin B-frags done
  // so the compiler emits no waitcnt for them inside the loop.
  {
#pragma unroll
    for (int r = 0; r < 4; ++r) {
      const int evr = evs[4 * q + r][255];
      const float* Ep = EW + (size_t)evr * R7 + j0 + nn;
      asm volatile("global_load_dword %0, %1, off" : "=v"(e0[r]) : "v"(Ep + g0 * HID) : "memory");
      if (two)
        asm volatile("global_load_dword %0, %1, off" : "=v"(e1[r]) : "v"(Ep + (g0 + 1) * HID) : "memory");
      else e1[r] = 0.0f;
    }
    asm volatile("s_waitcnt vmcnt(0)" ::: "memory");
    __builtin_amdgcn_sched_barrier(0);
#pragma unroll
    for (int kt = 0; kt < 8; ++kt) {
      asm volatile("" :: "v"(B0[kt]));
      if (two) asm volatile("" :: "v"(B1[kt]));
    }
  }

  auto body = [&](const int c, const int it, float& cp, float& cb) {
    const int   i   = 255 - it, t = i - 1;
    const int   cs  = c * 16 + seq;
    const int   ev  = evs[cs][i];
    const float dt  = dts[cs][i];
    const int   nc  = c ^ 1;
    const int   itn = (c == 0) ? it : it + 1;            // next half's iter
    const bool  spH = (c == 0) ? (it >= 1) : (it < 254); // next half consumes h
    const bool  spE = !(c == 1 && it == 254);

    // ---- W: spec h + spec EW + pub drained; 6 output stores may float ----
    asm volatile("s_waitcnt vmcnt(6)" ::: "memory");
    __builtin_amdgcn_sched_barrier(0);
    __builtin_amdgcn_s_barrier();  // B1: gbuf WAR-safe

    // ---- V: validate tags; slow-path reload (rare) ----
    f16x8 av[8];
    if (it > 0) {
      const unsigned wt = ((unsigned)it) << 16;
      unsigned ok = 0;
#pragma unroll
      for (int r = 0; r < 16; ++r) {
        u32x4 x = tv[r];
        ok |= (x[0] ^ wt) | (x[1] ^ wt) | (x[2] ^ wt) | (x[3] ^ wt);
      }
      if (__any((ok >> 16) != 0u)) {
        const u32* hp = thp + (size_t)(c * 2 + (it & 1)) * THBUF + (size_t)lane * 8;
        int gd = 0;
        for (;;) {
#pragma unroll
          for (int kt = 0; kt < 8; ++kt) {
            asm volatile("global_load_dwordx4 %0, %1, off sc0 sc1"
                         : "=v"(tv[2 * kt]) : "v"(hp + kt * 512) : "memory");
            asm volatile("global_load_dwordx4 %0, %1, off sc0 sc1"
                         : "=v"(tv[2 * kt + 1]) : "v"(hp + kt * 512 + 4) : "memory");
          }
          asm volatile("s_waitcnt vmcnt(0)" ::: "memory");
          __builtin_amdgcn_sched_barrier(0);
          ok = 0;
#pragma unroll
          for (int r = 0; r < 16; ++r) {
            u32x4 x = tv[r];
            ok |= (x[0] ^ wt) | (x[1] ^ wt) | (x[2] ^ wt) | (x[3] ^ wt);
          }
          if (!__any((ok >> 16) != 0u) || ++gd > (1 << 16)) break;  // bail: fail, no hang
        }
      }
      // ---- unpack low 16 bits -> A fragments ----
#pragma unroll
      for (int kt = 0; kt < 8; ++kt) {
        u32x4 lo = tv[2 * kt], hi = tv[2 * kt + 1];
        u32x4 w = { (lo[0] & 0xFFFFu) | (lo[1] << 16), (lo[2] & 0xFFFFu) | (lo[3] << 16),
                    (hi[0] & 0xFFFFu) | (hi[1] << 16), (hi[2] & 0xFFFFu) | (hi[3] << 16) };
        av[kt] = __builtin_bit_cast(f16x8, w);
      }
    }

    // ---- C-in from EW (consume e0/e1 BEFORE spec overwrites them) ----
    f32x4 acc0 = {e0[0], e0[1], e0[2], e0[3]};
    f32x4 acc1 = {e1[0], e1[1], e1[2], e1[3]};

    // ---- S: speculative issue for the NEXT half (RT hides under rest) ----
    if (spH) {
      const u32* hp = thp + (size_t)(nc * 2 + (itn & 1)) * THBUF + (size_t)lane * 8;
#pragma unroll
      for (int kt = 0; kt < 8; ++kt) {
        asm volatile("global_load_dwordx4 %0, %1, off sc0 sc1"
                     : "=v"(tv[2 * kt]) : "v"(hp + kt * 512) : "memory");
        asm volatile("global_load_dwordx4 %0, %1, off sc0 sc1"
                     : "=v"(tv[2 * kt + 1]) : "v"(hp + kt * 512 + 4) : "memory");
      }
    }
    if (spE) {
      const int inext = 255 - itn;
#pragma unroll
      for (int r = 0; r < 4; ++r) {
        const int evr = evs[nc * 16 + 4 * q + r][inext];
        const float* Ep = EW + (size_t)evr * R7 + j0 + nn;
        asm volatile("global_load_dword %0, %1, off" : "=v"(e0[r]) : "v"(Ep + g0 * HID) : "memory");
        if (two)
          asm volatile("global_load_dword %0, %1, off" : "=v"(e1[r]) : "v"(Ep + (g0 + 1) * HID) : "memory");
      }
    }

    // ---- M: MFMA ----
    if (it > 0) {
#pragma unroll
      for (int kt = 0; kt < 8; ++kt) {
        acc0 = __builtin_amdgcn_mfma_f32_16x16x32_f16(av[kt], B0[kt], acc0, 0, 0, 0);
        if (two)
          acc1 = __builtin_amdgcn_mfma_f32_16x16x32_f16(av[kt], B1[kt], acc1, 0, 0, 0);
      }
    }

    // ---- G: gate exchange. C/D: lane l, reg r -> D[seq=4*(l>>4)+r][n=l&15]
    *(f32x4*)&gbuf[g0][nn][4 * q] = acc0;
    if (two) *(f32x4*)&gbuf[g0 + 1][nn][4 * q] = acc1;
    asm volatile("s_waitcnt lgkmcnt(0)" ::: "memory");
    __builtin_amdgcn_s_barrier();  // B2
    __builtin_amdgcn_sched_barrier(0);

    // ---- EP: epilogue for (seq, jj) — pure LDS+VALU ----
    float zz[7];
#pragma unroll
    for (int g = 0; g < 7; ++g) zz[g] = gbuf[g][jj][seq];
    float gi = sigf(zz[0]), gf = sigf(zz[1]), go = sigf(zz[2]);
    float gz = tanh_f(zz[3]);
    float gib = sigf(zz[4]), gfb = sigf(zz[5]);
    float gd = softplusf(zz[6]);
    float cell = gf * cp + gi * gz;
    float cbar = gfb * cb + gib * gz;
    float hm   = go * tanh_f(cell);
    float dec  = __expf(-gd * dt);
    float cim  = cbar + (cell - cbar) * dec;
    float him  = go * tanh_f(cim);
    float msk  = (ev != NPAD) ? 1.0f : 0.0f;
    float cbm  = cbar * msk;
    float hn   = him * msk;
    cp = cim * msk;
    cb = cbm;

    // ---- U: publish tagged h' (fire-and-forget; tag makes it self-valid) ----
    if (it <= 253) {
      u32 pubv = (((unsigned)(it + 1)) << 16) |
                 (u32)__builtin_bit_cast(unsigned short, (hf)hn);
      u32* hw = thp + (size_t)(c * 2 + ((it + 1) & 1)) * THBUF;
      asm volatile("global_store_dword %0, %1, off sc0 sc1"
                   :: "v"(hw + idx_w), "v"(pubv) : "memory");
    }

    // ---- O: outputs (6 stores; float across the next half boundary) ----
    float* o = out + (size_t)(p * 32 + cs) * 65280 + (size_t)t * HID + j;
    asm volatile("global_store_dword %0, %1, off" :: "v"(o), "v"(cell) : "memory");
    asm volatile("global_store_dword %0, %1, off" :: "v"(o + OS), "v"(cbm) : "memory");
    asm volatile("global_store_dword %0, %1, off" :: "v"(o + 2 * OS), "v"(gd) : "memory");
    asm volatile("global_store_dword %0, %1, off" :: "v"(o + 3 * OS), "v"(go) : "memory");
    asm volatile("global_store_dword %0, %1, off" :: "v"(o + 4 * OS), "v"(hn) : "memory");
    asm volatile("global_store_dword %0, %1, off" :: "v"(o + 5 * OS), "v"(hm) : "memory");
  };

#pragma unroll 1
  for (int it = 0; it < 255; ++it) {
    body(0, it, cp0, cb0);
    body(1, it, cp1, cb1);
  }
}

// ---------------------------------------------------------------------------
extern "C" void kernel_launch(void* const* d_in, const int* in_sizes, int n_in,
                              void* d_out, int out_size, void* d_ws, size_t ws_size,
                              hipStream_t stream) {
  const int*   event = (const int*)d_in[0];
  const float* dtime = (const float*)d_in[1];
  const float* Emb   = (const float*)d_in[2];
  const float* W     = (const float*)d_in[3];
  const float* bias  = (const float*)d_in[4];
  float*       out   = (float*)d_out;

  char*  ws = (char*)d_ws;
  f16x8* Wf = (f16x8*)ws;                               // 917504 B
  float* EW = (float*)(ws + 917504);                    // 250880 B
  u32*   th = (u32*)(ws + 917504 + 250880);             // 4p*2c*2par*16KB = 262144 B

  // Tagged-h buffers MUST be zeroed each launch: tag sequences repeat across
  // graph replays and would alias stale data otherwise.
  hipMemsetAsync(ws + 917504 + 250880, 0, 262144, stream);
  repack_mfma<<<224, 256, 0, stream>>>(W, Wf);
  ew_kernel<<<3920, 256, 0, stream>>>(Emb, W, bias, EW);
  scan_mfma<<<64, 256, 0, stream>>>(event, dtime, EW, Wf, th, out);
}

// Round 6
// 1002.167 us; speedup vs baseline: 1.3905x; 1.3905x over previous
//
#include <hip/hip_runtime.h>
#include <cstddef>
#include <cstdint>

// CT-LSTM right-to-left scan, weight-stationary MFMA, 2-cohort, flag protocol
// (round-3 skeleton) + EW-slice in LDS + counted-vmcnt store floating.
// 128 seqs (B=16,P=8), T=256, H=256, 7H=1792 gate rows, VOCAB=35, IDX_PAD=34.
//
//   z = EW[event]  +  h @ W2^T        (W2 = W[:,256:512], f16)
//
// 16 slices x 4 super-groups = 64 blocks; block (b,p) holds B-fragments for
// hidden j in [16b,16b+16) resident in VGPRs, alternating 2 cohorts of 16
// seqs. EW restricted to this block's 16 columns = 15.7 KB -> LDS (loaded
// once; the per-half EW gather becomes conflict-cheap ds_reads, removing the
// ~900-cy beyond-L2 fetch that sat inside round 3's critical vmcnt(0)).
//
// Per-half VMEM order (all loop VMEM is inline asm or position-pinned
// atomics): [D flag(1S, tid0) | B h x8 L] ... [U pub(1S) J probe(1L) K out x6 S]
// In-order vmcnt retire (m135) makes the top-of-half wait vmcnt(6): retires
// pub+probe, lets the 6 output stores float a FULL half before E's vmcnt(0)
// collects them (round 3 drained them with zero slack). The top barrier then
// certifies all waves' pubs acked -> flag release hoisted to right after it
// (~700 cy earlier than round 3 -> better probe hit-rate downstream).

typedef _Float16 hf;
typedef _Float16 f16x8 __attribute__((ext_vector_type(8)));
typedef float    f32x4 __attribute__((ext_vector_type(4)));

#define HID  256
#define R7   1792
#define TT   256
#define NPAD 34
#define HBUF_HF 4096     // f16 elems per h buffer (16 seq x 256)

__device__ __forceinline__ float sigf(float x) { return 1.0f / (1.0f + __expf(-x)); }
__device__ __forceinline__ float tanh_f(float x) { return 1.0f - 2.0f / (__expf(2.0f * x) + 1.0f); }
__device__ __forceinline__ float softplusf(float x) {
  return fmaxf(x, 0.0f) + __logf(1.0f + __expf(-fabsf(x)));
}

// ---------------------------------------------------------------------------
// Repack W[:,256:512] into MFMA B-fragment order.
// Entry idx = ((b*7+g)*8 + kt)*64 + lane:
//   B[k = kt*32 + 8*(lane>>4) + e][n = lane&15] = W2[g*256 + 16b + (lane&15)][k]
__global__ __launch_bounds__(256) void repack_mfma(const float* __restrict__ W,
                                                   f16x8* __restrict__ Wf) {
  int idx  = blockIdx.x * 256 + threadIdx.x;  // [0, 57344)
  int lane = idx & 63;
  int kt   = (idx >> 6) & 7;
  int gb   = idx >> 9;            // b*7 + g
  int g    = gb % 7;
  int b    = gb / 7;
  int row  = g * HID + b * 16 + (lane & 15);
  int k0   = kt * 32 + (lane >> 4) * 8;
  const float* src = W + (size_t)row * 512 + 256 + k0;
  f16x8 o;
#pragma unroll
  for (int e = 0; e < 8; ++e) o[e] = (hf)src[e];
  Wf[idx] = o;
}

// ---------------------------------------------------------------------------
// EW[e][r] = sum_k Emb[e][k] * W[r][k] + b[r]   (e<35, r<1792, k<256)
__global__ __launch_bounds__(256) void ew_kernel(const float* __restrict__ Emb,
                                                 const float* __restrict__ W,
                                                 const float* __restrict__ bias,
                                                 float* __restrict__ EW) {
  int wid  = (blockIdx.x * 256 + threadIdx.x) >> 6;
  int lane = threadIdx.x & 63;
  int o    = wid * 4;
#pragma unroll
  for (int qq = 0; qq < 4; ++qq, ++o) {
    int e = o / R7;
    int r = o - e * R7;
    const float4 ev4 = *(const float4*)(Emb + e * HID + lane * 4);
    const float4 wv4 = *(const float4*)(W + (size_t)r * 512 + lane * 4);
    float acc = ev4.x * wv4.x + ev4.y * wv4.y + ev4.z * wv4.z + ev4.w * wv4.w;
#pragma unroll
    for (int m = 32; m >= 1; m >>= 1) acc += __shfl_xor(acc, m, 64);
    if (lane == 0) EW[o] = acc + bias[r];
  }
}

// ---------------------------------------------------------------------------
__global__ __launch_bounds__(256, 1) void scan_mfma(
    const int* __restrict__ event, const float* __restrict__ dtime,
    const float* __restrict__ EW, const f16x8* __restrict__ Wf,
    hf* __restrict__ hbuf, int* __restrict__ flags,
    float* __restrict__ out) {
  const int tid = threadIdx.x;
  const int b   = blockIdx.x & 15;   // hidden slice
  const int p   = blockIdx.x >> 4;   // super-group 0..3
  const int j0  = b * 16;
  const int wid = tid >> 6, lane = tid & 63;
  const int seq = tid >> 4, jj = tid & 15;   // epilogue ownership (per cohort)
  const int j   = j0 + jj;
  const int q   = lane >> 4, nn = lane & 15; // MFMA C/D coords

  __shared__ int   evs[32][TT];              // [cohort*16+seq][i]
  __shared__ float dts[32][TT];
  __shared__ __align__(16) float gbuf[7][16][20];  // [gate][n][seq] (pad 20)
  __shared__ float ews[35 * 7 * 17];         // EW slice [e][g][nn], pad 17

#pragma unroll 4
  for (int r = 0; r < 32; ++r) {
    evs[r][tid] = event[(size_t)(p * 32 + r) * TT + tid];
    dts[r][tid] = dtime[(size_t)(p * 32 + r) * TT + tid];
  }
  // EW slice -> LDS (35 ev x 7 gates x our 16 columns = 15.7 KB, once).
  for (int idx = tid; idx < 35 * 112; idx += 256) {
    int e  = idx / 112, r = idx - e * 112;
    int g  = r >> 4, n2 = r & 15;
    ews[(e * 7 + g) * 17 + n2] = EW[(size_t)e * R7 + g * HID + j0 + n2];
  }

  // Resident B fragments: wave w owns gates {2w, 2w+1} (w==3: gate 6 only).
  const int  g0  = 2 * wid;
  const bool two = (wid < 3);
  f16x8 B0[8], B1[8];
  {
    const f16x8* wsrc = Wf + (size_t)((b * 7 + g0) * 8) * 64 + lane;
#pragma unroll
    for (int kt = 0; kt < 8; ++kt) B0[kt] = wsrc[kt * 64];
    if (two) {
#pragma unroll
      for (int kt = 0; kt < 8; ++kt) B1[kt] = wsrc[(8 + kt) * 64];
    }
  }
  // Pin all prologue VMEM retired before the counted-vmcnt loop begins.
  asm volatile("s_waitcnt vmcnt(0)" ::: "memory");
  __builtin_amdgcn_sched_barrier(0);
#pragma unroll
  for (int kt = 0; kt < 8; ++kt) {
    asm volatile("" :: "v"(B0[kt]));
    if (two) asm volatile("" :: "v"(B1[kt]));
  }
  __syncthreads();

  int* flb = flags + p * 64;                 // [cohort][32-int padded]
  hf*  hpb = hbuf + (size_t)p * 4 * HBUF_HF; // [cohort][dbuf][4096]

  // h' store offset in A-fragment order (same lane->k map as the reader).
  const int off16 = ((j >> 5) * 64 + seq + 16 * ((j >> 3) & 3)) * 8 + (j & 7);
  const size_t OS = 8355840;  // per-output-tensor stride

  float cp0 = 0.f, cb0 = 0.f, cp1 = 0.f, cb1 = 0.f;
  int pr = 0;  // probe value; re-defined by the waiting asm at A each half

  auto body = [&](const int c, const int it, float& cp, float& cb) {
    const int   i   = 255 - it, t = i - 1;
    const int   cs  = c * 16 + seq;
    const int   ev  = evs[cs][i];
    const float dt  = dts[cs][i];
    const int   nc  = c ^ 1;
    const int   itn = (c == 0) ? it : it + 1;  // value released/probed

    // ---- A: retire [flag, pub, probe] of prev half; 6 outs keep floating.
    // "+v"(pr) makes this asm pr's def point: no use/copy before the wait.
    asm volatile("s_waitcnt vmcnt(6)" : "+v"(pr) :: "memory");
    __builtin_amdgcn_sched_barrier(0);
    __builtin_amdgcn_s_barrier();  // all waves' pubs acked; gbuf WAR-safe

    // ---- D: release flag for prev half's cohort (hoisted ~700cy vs R3) ----
    if (tid == 0 && itn > 0)
      __hip_atomic_store(&flb[nc * 32 + b], itn, __ATOMIC_RELAXED,
                         __HIP_MEMORY_SCOPE_AGENT);

    // ---- S: spin for own cohort's flag (probe usually hits) ----
    if (it > 0) {
      int pv = (nn == b) ? 0x7fffffff : pr;
      if (!__all(pv >= it)) {
        int gd = 0;
        for (;;) {  // relaxed poll: no cache invalidation
          int v = (nn == b) ? 0x7fffffff
                : __hip_atomic_load(&flb[c * 32 + nn], __ATOMIC_RELAXED,
                                    __HIP_MEMORY_SCOPE_AGENT);
          if (__all(v >= it) || ++gd > (1 << 20)) break;  // bail: fail, no hang
        }
      }
    }

    // ---- B: issue h loads (L3 RT partially hidden by EW gather below) ----
    f16x8 av[8];
    if (it > 0) {
      const hf* hp = hpb + (size_t)(c * 2 + (it & 1)) * HBUF_HF + (size_t)lane * 8;
#pragma unroll
      for (int kt = 0; kt < 8; ++kt)
        asm volatile("global_load_dwordx4 %0, %1, off sc0 sc1"
                     : "=v"(av[kt]) : "v"(hp + (size_t)kt * 512) : "memory");
    }

    // ---- EW C-in gather: pure LDS now (was the HBM-latency critical load) --
    float e0[4], e1[4];
#pragma unroll
    for (int r = 0; r < 4; ++r) {
      const int evr  = evs[c * 16 + 4 * q + r][i];
      const int base = (evr * 7 + g0) * 17 + nn;
      e0[r] = ews[base];
      e1[r] = two ? ews[base + 17] : 0.0f;
    }

    // ---- E: wait h (outs from last half have had a full half to ack) ----
    asm volatile("s_waitcnt vmcnt(0)" ::: "memory");
    __builtin_amdgcn_sched_barrier(0);
    if (it > 0) {
#pragma unroll
      for (int kt = 0; kt < 8; ++kt) asm volatile("" : "+v"(av[kt]));
    }

    // ---- M: MFMA, C-in = EW ----
    f32x4 acc0 = {e0[0], e0[1], e0[2], e0[3]};
    f32x4 acc1 = {e1[0], e1[1], e1[2], e1[3]};
    if (it > 0) {
#pragma unroll
      for (int kt = 0; kt < 8; ++kt) {
        acc0 = __builtin_amdgcn_mfma_f32_16x16x32_f16(av[kt], B0[kt], acc0, 0, 0, 0);
        if (two)
          acc1 = __builtin_amdgcn_mfma_f32_16x16x32_f16(av[kt], B1[kt], acc1, 0, 0, 0);
      }
    }

    // ---- G: gate exchange. C/D: lane l, reg r -> D[seq=4*(l>>4)+r][n=l&15]
    *(f32x4*)&gbuf[g0][nn][4 * q] = acc0;
    if (two) *(f32x4*)&gbuf[g0 + 1][nn][4 * q] = acc1;
    asm volatile("s_waitcnt lgkmcnt(0)" ::: "memory");
    __builtin_amdgcn_s_barrier();  // B2
    __builtin_amdgcn_sched_barrier(0);

    // ---- EP: epilogue for (seq, jj) — pure LDS+VALU ----
    float zz[7];
#pragma unroll
    for (int g = 0; g < 7; ++g) zz[g] = gbuf[g][jj][seq];
    float gi = sigf(zz[0]), gf = sigf(zz[1]), go = sigf(zz[2]);
    float gz = tanh_f(zz[3]);
    float gib = sigf(zz[4]), gfb = sigf(zz[5]);
    float gd = softplusf(zz[6]);
    float cell = gf * cp + gi * gz;
    float cbar = gfb * cb + gib * gz;
    float hm   = go * tanh_f(cell);
    float dec  = __expf(-gd * dt);
    float cim  = cbar + (cell - cbar) * dec;
    float him  = go * tanh_f(cim);
    float msk  = (ev != NPAD) ? 1.0f : 0.0f;
    float cbm  = cbar * msk;
    float hn   = him * msk;
    cp = cim * msk;
    cb = cbm;

    // ---- U: publish h' (sc0 sc1 write-through; acked by next A's count) ----
    unsigned short hb16 = __builtin_bit_cast(unsigned short, (hf)hn);
    unsigned nb = __shfl_down((unsigned)hb16, 1, 64);
    if (it < 254 && !(jj & 1)) {
      unsigned pack = (unsigned)hb16 | (nb << 16);
      hf* hw = hpb + (size_t)(c * 2 + ((it + 1) & 1)) * HBUF_HF;
      asm volatile("global_store_dword %0, %1, off sc0 sc1"
                   :: "v"((unsigned*)(hw + off16)), "v"(pack) : "memory");
    }

    // ---- J: probe next cohort's flags (retired by next A's vmcnt(6)) ----
    asm volatile("global_load_dword %0, %1, off sc0 sc1"
                 : "=v"(pr) : "v"(flb + nc * 32 + nn) : "memory");

    // ---- K: outputs — the 6 newest VMEM; float across the next boundary ----
    float* o = out + (size_t)(p * 32 + cs) * 65280 + (size_t)t * HID + j;
    asm volatile("global_store_dword %0, %1, off" :: "v"(o), "v"(cell) : "memory");
    asm volatile("global_store_dword %0, %1, off" :: "v"(o + OS), "v"(cbm) : "memory");
    asm volatile("global_store_dword %0, %1, off" :: "v"(o + 2 * OS), "v"(gd) : "memory");
    asm volatile("global_store_dword %0, %1, off" :: "v"(o + 3 * OS), "v"(go) : "memory");
    asm volatile("global_store_dword %0, %1, off" :: "v"(o + 4 * OS), "v"(hn) : "memory");
    asm volatile("global_store_dword %0, %1, off" :: "v"(o + 5 * OS), "v"(hm) : "memory");
  };

#pragma unroll 1
  for (int it = 0; it < 255; ++it) {
    body(0, it, cp0, cb0);
    body(1, it, cp1, cb1);
  }
}

// ---------------------------------------------------------------------------
extern "C" void kernel_launch(void* const* d_in, const int* in_sizes, int n_in,
                              void* d_out, int out_size, void* d_ws, size_t ws_size,
                              hipStream_t stream) {
  const int*   event = (const int*)d_in[0];
  const float* dtime = (const float*)d_in[1];
  const float* Emb   = (const float*)d_in[2];
  const float* W     = (const float*)d_in[3];
  const float* bias  = (const float*)d_in[4];
  float*       out   = (float*)d_out;

  char*  ws = (char*)d_ws;
  f16x8* Wf = (f16x8*)ws;                               // 917504 B
  float* EW = (float*)(ws + 917504);                    // 250880 B
  hf*    hb = (hf*)(ws + 917504 + 250880);              // 4p*2c*2buf*8KB = 131072 B
  int*   fl = (int*)(ws + 917504 + 250880 + 131072);    // 4p*2c*32 ints = 1024 B

  // Flags MUST be zeroed each launch (graph replay would see stale values).
  hipMemsetAsync(ws + 917504 + 250880, 0, 131072 + 1024, stream);
  repack_mfma<<<224, 256, 0, stream>>>(W, Wf);
  ew_kernel<<<3920, 256, 0, stream>>>(Emb, W, bias, EW);
  scan_mfma<<<64, 256, 0, stream>>>(event, dtime, EW, Wf, hb, fl, out);
}